// Round 5
// baseline (3758.742 us; speedup 1.0000x reference)
//
#include <hip/hip_runtime.h>
#include <cstdint>
#include <cstddef>

// RNN: B=256, T=512, H=512, I=64, O=24. fp32 in/out.
//
// v5 structure:
//  Path A2 (ws >= 256 MiB): K-split x2 across paired blocks.
//    ex/cnt live in the TAIL OF d_out (out_all fully overwrites d_out after
//    rnn_core2; xp_gemm re-zeroes cnt each launch -> graph-replay-safe).
//    1) xp_gemm: xp = W_ih x + b_ih + b_hh (f16, permuted) -> ws[0,128Mi);
//       zeroes sync counters.
//    2) rnn_core2: 32 blocks = (kb in {0,1}) x (g in 0..15). Block (kb,g)
//       holds W_hh[:, 256kb:256kb+256] entirely in regs (128 VGPR/lane) for
//       all 512 h-cols of batch group g. Per step: 4 sender waves store f32
//       partials for the partner's cols to ex (+release counter, agent
//       scope); 4 finalizer waves spin on partner counter (acquire), add
//       partner partials + xp, tanh, write h-half to LDS; hall history
//       stores DEFERRED one step (issued at next loop top, drained by that
//       step's barrier -> off critical path).
//       Deadlock-free: senders never wait; finalizers wait only on partner
//       senders. ex parity reuse protected by the 2-barrier chain.
//    3) out_all: full-chip epilogue out = tanh(h_all @ W_ho^T + b_ho).
//  Path A (ws >= 256 MiB but d_out too small): round-3 single-CU kernel.
//  Path C: self-contained fallback.

#define TSTEPS 512
#define HDIM   512
#define NIN    64
#define NOUT   24
#define BB     16
#define HPAD   520
#define XPAD   72
#define KHALF  256
#define HPAD2  264      // k-local h pitch (h16) for rnn_core2
// Path A split
#define NREG   49
#define NLDS   (64 - NREG)
// exchange sizes (elements)
#define EX_F32  (64 * 4096)   // 1 MiB
#define CNT_U32 64

typedef _Float16 h16;
typedef __attribute__((ext_vector_type(8))) _Float16 h16x8;
typedef __attribute__((ext_vector_type(4))) _Float16 h16x4;
typedef __attribute__((ext_vector_type(2))) _Float16 h16x2;
typedef __attribute__((ext_vector_type(4))) float    f32x4;
typedef __attribute__((ext_vector_type(2))) float    f32x2;

__device__ __forceinline__ float fast_tanh(float z) {
  float e = __builtin_amdgcn_exp2f(z * 2.8853900817779268f);
  return 1.0f - 2.0f * __builtin_amdgcn_rcpf(e + 1.0f);
}

__device__ __forceinline__ h16x8 cvt8(const float* __restrict__ p) {
  f32x4 f0 = *(const f32x4*)p;
  f32x4 f1 = *(const f32x4*)(p + 4);
  h16x8 a;
  #pragma unroll
  for (int j = 0; j < 4; ++j) { a[j] = (h16)f0[j]; a[4 + j] = (h16)f1[j]; }
  return a;
}

// ---------------- Prologue: xp = W_ih x + b_ih + b_hh, permuted f16 ----------
// chunk ((t*16+g)*8+wave)*64+lane holds 16 h16:
// [m*4+i] = xp[batch=16g+(lane&15)][t][col=64*wave+16m+4*(lane>>4)+i]
__global__ __launch_bounds__(512)
void xp_gemm(const float* __restrict__ x, const float* __restrict__ Wih,
             const float* __restrict__ bih, const float* __restrict__ bhh,
             h16* __restrict__ xp, unsigned* __restrict__ cnt)
{
  const int tid  = threadIdx.x;
  const int wave = tid >> 6;
  const int lane = tid & 63;
  const int lr   = lane & 15;
  const int lk   = lane >> 4;
  const int blk  = blockIdx.x & 15;
  const int tc   = blockIdx.x >> 4;
  const int c0   = wave * 64;

  if (cnt && blockIdx.x == 0 && tid < CNT_U32) cnt[tid] = 0u;  // replay-safe re-init

  h16x8 A[4][2];
  #pragma unroll
  for (int m = 0; m < 4; ++m)
    #pragma unroll
    for (int s = 0; s < 2; ++s)
      A[m][s] = cvt8(Wih + (size_t)(c0 + 16 * m + lr) * NIN + 32 * s + 8 * lk);

  f32x4 bias[4];
  #pragma unroll
  for (int m = 0; m < 4; ++m) {
    const int c = c0 + 16 * m + 4 * lk;
    f32x4 bi = *(const f32x4*)&bih[c];
    f32x4 bh = *(const f32x4*)&bhh[c];
    bias[m] = bi + bh;
  }

  const float* xrow = x + (size_t)(16 * blk + lr) * (TSTEPS * NIN);

  for (int j = 0; j < 32; ++j) {
    const int t = tc * 32 + j;
    f32x4 acc[4];
    #pragma unroll
    for (int m = 0; m < 4; ++m) acc[m] = bias[m];
    #pragma unroll
    for (int s = 0; s < 2; ++s) {
      h16x8 bx = cvt8(xrow + (size_t)t * NIN + 32 * s + 8 * lk);
      #pragma unroll
      for (int m = 0; m < 4; ++m)
        acc[m] = __builtin_amdgcn_mfma_f32_16x16x32_f16(A[m][s], bx, acc[m], 0, 0, 0);
    }
    h16x8 c0v, c1v;
    #pragma unroll
    for (int i = 0; i < 4; ++i) {
      c0v[i]     = (h16)acc[0][i];
      c0v[4 + i] = (h16)acc[1][i];
      c1v[i]     = (h16)acc[2][i];
      c1v[4 + i] = (h16)acc[3][i];
    }
    h16* p = xp + ((((size_t)t * 16 + blk) * 8 + wave) * 64 + lane) * 16;
    *(h16x8*)p       = c0v;
    *(h16x8*)(p + 8) = c1v;
  }
}

// ---------------- Path A2: K-split recurrence --------------------------------
__global__ __launch_bounds__(512, 2)
void rnn_core2(const float* __restrict__ Whh, const h16* __restrict__ xp,
               h16* __restrict__ hall, float* __restrict__ ex,
               unsigned* __restrict__ cnt)
{
  __shared__ h16 hl[2][16 * HPAD2];   // 16896 B: [buf][batch_row][k-local col]

  const int tid  = threadIdx.x;
  const int wave = tid >> 6;
  const int lane = tid & 63;
  const int lr   = lane & 15;
  const int lk   = lane >> 4;
  const int kb   = blockIdx.x >> 4;       // k-half owned by this block
  const int g    = blockIdx.x & 15;       // batch group
  const int wq   = wave & 3;
  const bool fin = ((wave >> 2) == kb);   // finalizer: cols lie in own k-half
  const int b0   = g * 16;

  // A-frags: cols 64*wave+16m+lr (all 512 across 8 waves), own k-half only.
  // 32 slots x 4 VGPRs = 128 VGPRs -> whole W_hh k-slice register-resident.
  h16x8 areg[8][4];   // [s][m]
  #pragma unroll
  for (int s = 0; s < 8; ++s)
    #pragma unroll
    for (int m = 0; m < 4; ++m)
      areg[s][m] = cvt8(Whh + (size_t)(64 * wave + 16 * m + lr) * HDIM
                        + KHALF * kb + 32 * s + 8 * lk);

  for (int idx = tid; idx < 16 * HPAD2; idx += 512) hl[0][idx] = (h16)0.f;
  __syncthreads();

  // xp preload (finalizers only; their cols == their xp chunk)
  h16x8 xr0, xr1;
  if (fin) {
    const h16* p = xp + (((size_t)g * 8 + wave) * 64 + lane) * 16;
    xr0 = *(const h16x8*)p;
    xr1 = *(const h16x8*)(p + 8);
  }

  unsigned* mycnt   = &cnt[g * 2 + kb];
  unsigned* partcnt = &cnt[g * 2 + (1 - kb)];

  h16x4 pend[4];
  h16*  pendRow = hall;   // dummy init

  for (int t = 0; t < TSTEPS; ++t) {
    // issue DEFERRED hall stores for step t-1 (drained by this step's barrier)
    if (fin && t > 0) {
      #pragma unroll
      for (int m = 0; m < 4; ++m)
        *(h16x4*)(pendRow + 16 * m) = pend[m];
    }

    f32x4 acc[4];
    if (fin) {
      #pragma unroll
      for (int i = 0; i < 4; ++i) {
        acc[0][i] = (float)xr0[i];
        acc[1][i] = (float)xr0[4 + i];
        acc[2][i] = (float)xr1[i];
        acc[3][i] = (float)xr1[4 + i];
      }
      const int tn = (t + 1 < TSTEPS) ? (t + 1) : t;
      const h16* p = xp + ((((size_t)tn * 16 + g) * 8 + wave) * 64 + lane) * 16;
      xr0 = *(const h16x8*)p;
      xr1 = *(const h16x8*)(p + 8);
    } else {
      #pragma unroll
      for (int m = 0; m < 4; ++m) { acc[m][0]=0.f; acc[m][1]=0.f; acc[m][2]=0.f; acc[m][3]=0.f; }
    }

    // partials over own k-half
    const h16* hb = hl[t & 1];
    #pragma unroll
    for (int s = 0; s < 8; ++s) {
      h16x8 bh = *(const h16x8*)&hb[lr * HPAD2 + 32 * s + 8 * lk];
      #pragma unroll
      for (int m = 0; m < 4; ++m)
        acc[m] = __builtin_amdgcn_mfma_f32_16x16x32_f16(areg[s][m], bh, acc[m], 0, 0, 0);
    }

    if (!fin) {
      // send partials for the partner's cols
      float* exw = ex + ((size_t)((g * 2 + kb) * 2 + (t & 1)) << 12);
      #pragma unroll
      for (int m = 0; m < 4; ++m)
        *(f32x4*)&exw[((wq * 16 + m * 4 + lk) << 6) + lr * 4] = acc[m];
      if (lane == 0)
        __hip_atomic_fetch_add(mycnt, 1u, __ATOMIC_RELEASE, __HIP_MEMORY_SCOPE_AGENT);
    } else {
      // receive partner partials for own cols, finalize h
      const unsigned tgt = 4u * (unsigned)(t + 1);
      while (__hip_atomic_load(partcnt, __ATOMIC_ACQUIRE, __HIP_MEMORY_SCOPE_AGENT) < tgt)
        __builtin_amdgcn_s_sleep(1);
      const float* exr = ex + ((size_t)((g * 2 + (1 - kb)) * 2 + (t & 1)) << 12);
      h16* hn = hl[(t + 1) & 1];
      #pragma unroll
      for (int m = 0; m < 4; ++m) {
        f32x4 pp = *(const f32x4*)&exr[((wq * 16 + m * 4 + lk) << 6) + lr * 4];
        h16x4 hv;
        #pragma unroll
        for (int i = 0; i < 4; ++i) hv[i] = (h16)fast_tanh(acc[m][i] + pp[i]);
        *(h16x4*)&hn[lr * HPAD2 + 64 * wq + 16 * m + 4 * lk] = hv;
        pend[m] = hv;
      }
      pendRow = hall + ((size_t)t * 256 + b0 + lr) * HDIM + KHALF * kb + 64 * wq + 4 * lk;
    }

    __syncthreads();
  }

  // flush final pending hall stores (t = 511)
  if (fin) {
    #pragma unroll
    for (int m = 0; m < 4; ++m)
      *(h16x4*)(pendRow + 16 * m) = pend[m];
  }
}

// ---------------- Epilogue: out = tanh(h_all @ W_ho^T + b_ho) ----------------
__global__ __launch_bounds__(512)
void out_all(const h16* __restrict__ hall, const float* __restrict__ Who,
             const float* __restrict__ bho, float* __restrict__ out)
{
  __shared__ h16 wholds[NOUT * HPAD];   // 24960 B

  const int tid  = threadIdx.x;
  const int wave = tid >> 6;
  const int lane = tid & 63;
  const int lr   = lane & 15;
  const int lk   = lane >> 4;

  for (int idx = tid; idx < NOUT * HDIM; idx += 512) {
    int r = idx >> 9, k = idx & 511;
    wholds[r * HPAD + k] = (h16)Who[idx];
  }

  f32x4 o0, o1;
  { o0 = *(const f32x4*)&bho[lk * 4]; }
  { int ob = 16 + lk * 4;
    if (ob < NOUT) o1 = *(const f32x4*)&bho[ob];
    else { o1[0] = 0.f; o1[1] = 0.f; o1[2] = 0.f; o1[3] = 0.f; } }
  __syncthreads();

  const int rt = blockIdx.x * 8 + wave;
  const int t  = rt >> 4;
  const int b  = (rt & 15) * 16 + lr;
  const int row1 = (16 + lr < NOUT) ? (16 + lr) : (8 + lr);

  const h16* hrow = hall + ((size_t)t * 256 + b) * HDIM + lk * 8;

  #pragma unroll
  for (int s = 0; s < 16; ++s) {
    h16x8 bh = *(const h16x8*)(hrow + 32 * s);
    h16x8 a0 = *(const h16x8*)&wholds[lr * HPAD + s * 32 + lk * 8];
    h16x8 a1 = *(const h16x8*)&wholds[row1 * HPAD + s * 32 + lk * 8];
    o0 = __builtin_amdgcn_mfma_f32_16x16x32_f16(a0, bh, o0, 0, 0, 0);
    o1 = __builtin_amdgcn_mfma_f32_16x16x32_f16(a1, bh, o1, 0, 0, 0);
  }

  float* op = out + ((size_t)b * TSTEPS + t) * NOUT;
  f32x4 v0;
  #pragma unroll
  for (int i = 0; i < 4; ++i) v0[i] = fast_tanh(o0[i]);
  *(f32x4*)(op + lk * 4) = v0;
  if (lk < 2) {
    f32x4 v1;
    #pragma unroll
    for (int i = 0; i < 4; ++i) v1[i] = fast_tanh(o1[i]);
    *(f32x4*)(op + 16 + lk * 4) = v1;
  }
}

// ---------------- Path A fallback: round-3 single-CU recurrence --------------
__global__ __launch_bounds__(512, 2)
void rnn_core(const float* __restrict__ Whh, const h16* __restrict__ xp,
              h16* __restrict__ hall)
{
  __shared__ h16 hbuf[2][BB * HPAD];
  __shared__ h16 aslice[NLDS * 8 * 512];

  const int tid  = threadIdx.x;
  const int wave = tid >> 6;
  const int lane = tid & 63;
  const int lr   = lane & 15;
  const int lk   = lane >> 4;
  const int blk  = blockIdx.x;
  const int b0   = blk * BB;
  const int wc0  = wave * 64;

  h16x8 areg[NREG];
  #pragma unroll
  for (int s = 0; s < 16; ++s) {
    #pragma unroll
    for (int m = 0; m < 4; ++m) {
      h16x8 a = cvt8(Whh + (size_t)(wc0 + 16 * m + lr) * HDIM + 32 * s + 8 * lk);
      const int id = s * 4 + m;
      if (id < NREG) areg[id] = a;
      else *(h16x8*)&aslice[(size_t)((id - NREG) * 8 + wave) * 512 + lane * 8] = a;
    }
  }

  for (int idx = tid; idx < BB * HPAD; idx += 512) hbuf[0][idx] = (h16)0.f;
  __syncthreads();

  h16x8 xr0, xr1;
  {
    const h16* p = xp + (((size_t)blk * 8 + wave) * 64 + lane) * 16;
    xr0 = *(const h16x8*)p;
    xr1 = *(const h16x8*)(p + 8);
  }

  for (int t = 0; t < TSTEPS; ++t) {
    const h16* hb = hbuf[t & 1];
    h16*       hn = hbuf[(t + 1) & 1];

    f32x4 acc[4];
    #pragma unroll
    for (int i = 0; i < 4; ++i) {
      acc[0][i] = (float)xr0[i];
      acc[1][i] = (float)xr0[4 + i];
      acc[2][i] = (float)xr1[i];
      acc[3][i] = (float)xr1[4 + i];
    }
    {
      const int tn = (t + 1 < TSTEPS) ? (t + 1) : t;
      const h16* p = xp + ((((size_t)tn * 16 + blk) * 8 + wave) * 64 + lane) * 16;
      xr0 = *(const h16x8*)p;
      xr1 = *(const h16x8*)(p + 8);
    }

    #pragma unroll
    for (int s = 0; s < 16; ++s) {
      h16x8 bh = *(const h16x8*)&hb[lr * HPAD + 32 * s + 8 * lk];
      #pragma unroll
      for (int m = 0; m < 4; ++m) {
        const int id = s * 4 + m;
        h16x8 a = (id < NREG)
            ? areg[id]
            : *(const h16x8*)&aslice[(size_t)((id - NREG) * 8 + wave) * 512 + lane * 8];
        acc[m] = __builtin_amdgcn_mfma_f32_16x16x32_f16(a, bh, acc[m], 0, 0, 0);
      }
    }

    h16* hrow = hall + ((size_t)t * 256 + b0 + lr) * HDIM + wc0 + lk * 4;
    #pragma unroll
    for (int m = 0; m < 4; ++m) {
      h16x4 hv;
      #pragma unroll
      for (int i = 0; i < 4; ++i) hv[i] = (h16)fast_tanh(acc[m][i]);
      *(h16x4*)&hn[lr * HPAD + wc0 + 16 * m + 4 * lk] = hv;
      *(h16x4*)(hrow + 16 * m) = hv;
    }

    __syncthreads();
  }
}

// ---------------- Path C: fully self-contained fallback ----------------------
__device__ __forceinline__ void out_proj(
    int t, const h16* __restrict__ hb, const h16* __restrict__ who,
    f32x4 bho0, f32x4 bho1, float* __restrict__ out, int b0, int lr, int lk)
{
  f32x4 o0 = bho0, o1 = bho1;
  const int row1 = (16 + lr < NOUT) ? (16 + lr) : (8 + lr);
  #pragma unroll
  for (int s = 0; s < 16; ++s) {
    h16x8 bh = *(const h16x8*)&hb[lr * HPAD + s * 32 + lk * 8];
    h16x8 a0 = *(const h16x8*)&who[lr * HPAD + s * 32 + lk * 8];
    h16x8 a1 = *(const h16x8*)&who[row1 * HPAD + s * 32 + lk * 8];
    o0 = __builtin_amdgcn_mfma_f32_16x16x32_f16(a0, bh, o0, 0, 0, 0);
    o1 = __builtin_amdgcn_mfma_f32_16x16x32_f16(a1, bh, o1, 0, 0, 0);
  }
  float* op = out + ((size_t)(b0 + lr) * TSTEPS + t) * NOUT;
  f32x4 v0;
  #pragma unroll
  for (int i = 0; i < 4; ++i) v0[i] = fast_tanh(o0[i]);
  *(f32x4*)(op + lk * 4) = v0;
  if (lk < 2) {
    f32x4 v1;
    #pragma unroll
    for (int i = 0; i < 4; ++i) v1[i] = fast_tanh(o1[i]);
    *(f32x4*)(op + 16 + lk * 4) = v1;
  }
}

__global__ __launch_bounds__(512, 2)
void rnn_fused(const float* __restrict__ x,
               const float* __restrict__ Wih,
               const float* __restrict__ Whh,
               const float* __restrict__ bih,
               const float* __restrict__ bhh,
               const float* __restrict__ Who,
               const float* __restrict__ bho,
               float* __restrict__ out)
{
  __shared__ h16 hbuf[2][BB * HPAD];
  __shared__ h16 xbuf[2][BB * XPAD];
  __shared__ h16 wholds[NOUT * HPAD];

  const int tid  = threadIdx.x;
  const int wave = tid >> 6;
  const int lane = tid & 63;
  const int lr   = lane & 15;
  const int lk   = lane >> 4;
  const int b0   = blockIdx.x * BB;
  const int wc0  = wave * 64;

  h16x8 a_rec[4][16];
  #pragma unroll
  for (int m = 0; m < 4; ++m) {
    const int row = wc0 + m * 16 + lr;
    #pragma unroll
    for (int s = 0; s < 16; ++s)
      a_rec[m][s] = cvt8(Whh + (size_t)row * HDIM + s * 32 + lk * 8);
  }
  h16x8 a_ih[4][2];
  #pragma unroll
  for (int m = 0; m < 4; ++m) {
    const int row = wc0 + m * 16 + lr;
    #pragma unroll
    for (int s = 0; s < 2; ++s)
      a_ih[m][s] = cvt8(Wih + (size_t)row * NIN + s * 32 + lk * 8);
  }
  f32x4 biasv[4];
  #pragma unroll
  for (int m = 0; m < 4; ++m) {
    const int c = wc0 + m * 16 + lk * 4;
    f32x4 bi = *(const f32x4*)&bih[c];
    f32x4 bh2 = *(const f32x4*)&bhh[c];
    biasv[m] = bi + bh2;
  }
  f32x4 bho0, bho1;
  { bho0 = *(const f32x4*)&bho[lk * 4]; }
  { int ob = 16 + lk * 4;
    if (ob < NOUT) bho1 = *(const f32x4*)&bho[ob];
    else { bho1[0] = 0.f; bho1[1] = 0.f; bho1[2] = 0.f; bho1[3] = 0.f; } }

  for (int idx = tid; idx < NOUT * HDIM; idx += 512) {
    int r = idx >> 9, k = idx & 511;
    wholds[r * HPAD + k] = (h16)Who[idx];
  }
  for (int idx = tid; idx < BB * HPAD; idx += 512) hbuf[0][idx] = (h16)0.f;
  {
    int r = tid >> 5, c2 = (tid & 31) * 2;
    f32x2 v = *(const f32x2*)(x + ((size_t)(b0 + r) * TSTEPS + 0) * NIN + c2);
    h16x2 pk = { (h16)v.x, (h16)v.y };
    *(h16x2*)&xbuf[0][r * XPAD + c2] = pk;
  }
  __syncthreads();

  for (int t = 0; t < TSTEPS; ++t) {
    const h16* hb = hbuf[t & 1];
    h16*       hn = hbuf[(t + 1) & 1];
    const h16* xb = xbuf[t & 1];
    h16*       xn = xbuf[(t + 1) & 1];

    if (t > 0 && wave == ((t - 1) & 7))
      out_proj(t - 1, hb, wholds, bho0, bho1, out, b0, lr, lk);

    const int tl = (t + 1 < TSTEPS) ? (t + 1) : (TSTEPS - 1);
    const int xr = tid >> 5, xc = (tid & 31) * 2;
    f32x2 xv = *(const f32x2*)(x + ((size_t)(b0 + xr) * TSTEPS + tl) * NIN + xc);

    f32x4 acc[4];
    #pragma unroll
    for (int m = 0; m < 4; ++m) acc[m] = biasv[m];
    #pragma unroll
    for (int s = 0; s < 2; ++s) {
      h16x8 bx = *(const h16x8*)&xb[lr * XPAD + s * 32 + lk * 8];
      #pragma unroll
      for (int m = 0; m < 4; ++m)
        acc[m] = __builtin_amdgcn_mfma_f32_16x16x32_f16(a_ih[m][s], bx, acc[m], 0, 0, 0);
    }
    #pragma unroll
    for (int s = 0; s < 16; ++s) {
      h16x8 bh = *(const h16x8*)&hb[lr * HPAD + 32 * s + 8 * lk];
      #pragma unroll
      for (int m = 0; m < 4; ++m)
        acc[m] = __builtin_amdgcn_mfma_f32_16x16x32_f16(a_rec[m][s], bh, acc[m], 0, 0, 0);
    }
    #pragma unroll
    for (int m = 0; m < 4; ++m) {
      h16x4 hv;
      #pragma unroll
      for (int i = 0; i < 4; ++i) hv[i] = (h16)fast_tanh(acc[m][i]);
      *(h16x4*)&hn[lr * HPAD + wc0 + 16 * m + 4 * lk] = hv;
    }
    {
      h16x2 pk = { (h16)xv.x, (h16)xv.y };
      *(h16x2*)&xn[xr * XPAD + xc] = pk;
    }
    __syncthreads();
  }

  if (wave == ((TSTEPS - 1) & 7))
    out_proj(TSTEPS - 1, hbuf[TSTEPS & 1], wholds, bho0, bho1, out, b0, lr, lk);
}

extern "C" void kernel_launch(void* const* d_in, const int* in_sizes, int n_in,
                              void* d_out, int out_size, void* d_ws, size_t ws_size,
                              hipStream_t stream) {
  (void)in_sizes; (void)n_in;
  const float* x   = (const float*)d_in[0];
  const float* Wih = (const float*)d_in[1];
  const float* Whh = (const float*)d_in[2];
  const float* bih = (const float*)d_in[3];
  const float* bhh = (const float*)d_in[4];
  const float* Who = (const float*)d_in[5];
  const float* bho = (const float*)d_in[6];
  float* out = (float*)d_out;

  const size_t XP_BYTES   = (size_t)TSTEPS * 256 * HDIM * sizeof(h16);  // 128 MiB
  const size_t HALL_BYTES = (size_t)TSTEPS * 256 * HDIM * sizeof(h16);  // 128 MiB
  const int    EX_TAIL    = EX_F32 + CNT_U32;   // carved from d_out (f32 slots)

  if (ws_size >= XP_BYTES + HALL_BYTES && out_size >= EX_TAIL + 16) {
    h16*      xp   = (h16*)d_ws;
    h16*      hall = (h16*)((char*)d_ws + XP_BYTES);
    float*    ex   = out + ((size_t)out_size - EX_TAIL);   // 16B-aligned tail
    unsigned* cnt  = (unsigned*)(ex + EX_F32);
    xp_gemm<<<dim3(256), dim3(512), 0, stream>>>(x, Wih, bih, bhh, xp, cnt);
    rnn_core2<<<dim3(32), dim3(512), 0, stream>>>(Whh, xp, hall, ex, cnt);
    out_all<<<dim3(1024), dim3(512), 0, stream>>>(hall, Who, bho, out);
  } else if (ws_size >= XP_BYTES + HALL_BYTES) {
    h16* xp   = (h16*)d_ws;
    h16* hall = (h16*)((char*)d_ws + XP_BYTES);
    xp_gemm<<<dim3(256), dim3(512), 0, stream>>>(x, Wih, bih, bhh, xp, nullptr);
    rnn_core<<<dim3(256 / BB), dim3(512), 0, stream>>>(Whh, xp, hall);
    out_all<<<dim3(1024), dim3(512), 0, stream>>>(hall, Who, bho, out);
  } else {
    rnn_fused<<<dim3(256 / BB), dim3(512), 0, stream>>>(x, Wih, Whh, bih, bhh, Who, bho, out);
  }
}

// Round 6
// 2713.188 us; speedup vs baseline: 1.3854x; 1.3854x over previous
//
#include <hip/hip_runtime.h>
#include <cstdint>
#include <cstddef>

// RNN: B=256, T=512, H=512, I=64, O=24. fp32 in/out.
//
// v6 structure:
//  Path A3 (ws >= 256 MiB):
//    1) xp_gemm: xp[b][t][:] = W_ih x + b_ih + b_hh (f16, permuted) -> ws[0,128Mi)
//    2) rnn_core3: 8 blocks x 512 thr; each block carries TWO 16-row batch
//       groups through the recurrence. W_hh f16 fragments: 49 slots in regs
//       (196/lane, AGPR-eligible) + 15 slots in LDS. Each weight fragment
//       read feeds TWO MFMAs (group A + group B) -> LDS weight stream
//       amortized 2x, and group B's reads/MFMAs fill group A's pipeline
//       bubbles (the barrier-tail stall). h single-buffered per group,
//       2 barriers per step-pair. h history streamed to ws[128Mi,256Mi).
//    3) out_all: full-chip epilogue out = tanh(h_all @ W_ho^T + b_ho).
//  Fallback: self-contained round-0 kernel (~4.4 ms).
//
//  Round-5 lesson (measured): per-step cross-CU sync via agent-scope
//  acquire/release = L2 writeback/invalidate per step (~6 us) -> any
//  multi-CU split of the recurrence loses. Stay single-CU per recurrence,
//  scale by batch groups per CU instead.

#define TSTEPS 512
#define HDIM   512
#define NIN    64
#define NOUT   24
#define BB     16
#define HPAD   520
#define XPAD   72
#define NREG   49
#define NLDS   (64 - NREG)   // 15

typedef _Float16 h16;
typedef __attribute__((ext_vector_type(8))) _Float16 h16x8;
typedef __attribute__((ext_vector_type(4))) _Float16 h16x4;
typedef __attribute__((ext_vector_type(2))) _Float16 h16x2;
typedef __attribute__((ext_vector_type(4))) float    f32x4;
typedef __attribute__((ext_vector_type(2))) float    f32x2;

__device__ __forceinline__ float fast_tanh(float z) {
  float e = __builtin_amdgcn_exp2f(z * 2.8853900817779268f);
  return 1.0f - 2.0f * __builtin_amdgcn_rcpf(e + 1.0f);
}

__device__ __forceinline__ h16x8 cvt8(const float* __restrict__ p) {
  f32x4 f0 = *(const f32x4*)p;
  f32x4 f1 = *(const f32x4*)(p + 4);
  h16x8 a;
  #pragma unroll
  for (int j = 0; j < 4; ++j) { a[j] = (h16)f0[j]; a[4 + j] = (h16)f1[j]; }
  return a;
}

// ---------------- Prologue: xp = W_ih x + b_ih + b_hh, permuted f16 ----------
// chunk ((t*16+g)*8+wave)*64+lane holds 16 h16:
// [m*4+i] = xp[batch=16g+(lane&15)][t][col=64*wave+16m+4*(lane>>4)+i]
__global__ __launch_bounds__(512)
void xp_gemm(const float* __restrict__ x, const float* __restrict__ Wih,
             const float* __restrict__ bih, const float* __restrict__ bhh,
             h16* __restrict__ xp)
{
  const int tid  = threadIdx.x;
  const int wave = tid >> 6;
  const int lane = tid & 63;
  const int lr   = lane & 15;
  const int lk   = lane >> 4;
  const int blk  = blockIdx.x & 15;
  const int tc   = blockIdx.x >> 4;
  const int c0   = wave * 64;

  h16x8 A[4][2];
  #pragma unroll
  for (int m = 0; m < 4; ++m)
    #pragma unroll
    for (int s = 0; s < 2; ++s)
      A[m][s] = cvt8(Wih + (size_t)(c0 + 16 * m + lr) * NIN + 32 * s + 8 * lk);

  f32x4 bias[4];
  #pragma unroll
  for (int m = 0; m < 4; ++m) {
    const int c = c0 + 16 * m + 4 * lk;
    f32x4 bi = *(const f32x4*)&bih[c];
    f32x4 bh = *(const f32x4*)&bhh[c];
    bias[m] = bi + bh;
  }

  const float* xrow = x + (size_t)(16 * blk + lr) * (TSTEPS * NIN);

  for (int j = 0; j < 32; ++j) {
    const int t = tc * 32 + j;
    f32x4 acc[4];
    #pragma unroll
    for (int m = 0; m < 4; ++m) acc[m] = bias[m];
    #pragma unroll
    for (int s = 0; s < 2; ++s) {
      h16x8 bx = cvt8(xrow + (size_t)t * NIN + 32 * s + 8 * lk);
      #pragma unroll
      for (int m = 0; m < 4; ++m)
        acc[m] = __builtin_amdgcn_mfma_f32_16x16x32_f16(A[m][s], bx, acc[m], 0, 0, 0);
    }
    h16x8 c0v, c1v;
    #pragma unroll
    for (int i = 0; i < 4; ++i) {
      c0v[i]     = (h16)acc[0][i];
      c0v[4 + i] = (h16)acc[1][i];
      c1v[i]     = (h16)acc[2][i];
      c1v[4 + i] = (h16)acc[3][i];
    }
    h16* p = xp + ((((size_t)t * 16 + blk) * 8 + wave) * 64 + lane) * 16;
    *(h16x8*)p       = c0v;
    *(h16x8*)(p + 8) = c1v;
  }
}

// ---------------- Path A3: dual-batch-group recurrence -----------------------
__global__ __launch_bounds__(512, 2)
void rnn_core3(const float* __restrict__ Whh, const h16* __restrict__ xp,
               h16* __restrict__ hall)
{
  __shared__ h16 hA[16 * HPAD];             // 16640 B  h state, group A
  __shared__ h16 hB[16 * HPAD];             // 16640 B  h state, group B
  __shared__ h16 aslice[NLDS * 8 * 512];    // 122880 B -> total 156160 B

  const int tid  = threadIdx.x;
  const int wave = tid >> 6;
  const int lane = tid & 63;
  const int lr   = lane & 15;
  const int lk   = lane >> 4;
  const int blk  = blockIdx.x;        // 0..7
  const int gA   = blk * 2;
  const int gB   = blk * 2 + 1;
  const int b0   = blk * 32;
  const int wc0  = wave * 64;

  // W_hh fragments: slot id = s*4+m; id < NREG -> regs, else LDS.
  h16x8 areg[NREG];
  #pragma unroll
  for (int s = 0; s < 16; ++s) {
    #pragma unroll
    for (int m = 0; m < 4; ++m) {
      h16x8 a = cvt8(Whh + (size_t)(wc0 + 16 * m + lr) * HDIM + 32 * s + 8 * lk);
      const int id = s * 4 + m;
      if (id < NREG) areg[id] = a;
      else *(h16x8*)&aslice[(size_t)((id - NREG) * 8 + wave) * 512 + lane * 8] = a;
    }
  }

  for (int idx = tid; idx < 16 * HPAD; idx += 512) {
    hA[idx] = (h16)0.f;
    hB[idx] = (h16)0.f;
  }
  __syncthreads();

  // preload xp(0) for both groups
  h16x8 xa0, xa1, xb0, xb1;
  {
    const h16* pA = xp + (((size_t)gA * 8 + wave) * 64 + lane) * 16;
    const h16* pB = xp + (((size_t)gB * 8 + wave) * 64 + lane) * 16;
    xa0 = *(const h16x8*)pA; xa1 = *(const h16x8*)(pA + 8);
    xb0 = *(const h16x8*)pB; xb1 = *(const h16x8*)(pB + 8);
  }

  for (int t = 0; t < TSTEPS; ++t) {
    // acc init from prefetched xp(t)
    f32x4 accA[4], accB[4];
    #pragma unroll
    for (int i = 0; i < 4; ++i) {
      accA[0][i] = (float)xa0[i];     accA[1][i] = (float)xa0[4 + i];
      accA[2][i] = (float)xa1[i];     accA[3][i] = (float)xa1[4 + i];
      accB[0][i] = (float)xb0[i];     accB[1][i] = (float)xb0[4 + i];
      accB[2][i] = (float)xb1[i];     accB[3][i] = (float)xb1[4 + i];
    }

    // prefetch xp(t+1), both groups
    {
      const int tn = (t + 1 < TSTEPS) ? (t + 1) : t;
      const h16* pA = xp + ((((size_t)tn * 16 + gA) * 8 + wave) * 64 + lane) * 16;
      const h16* pB = xp + ((((size_t)tn * 16 + gB) * 8 + wave) * 64 + lane) * 16;
      xa0 = *(const h16x8*)pA; xa1 = *(const h16x8*)(pA + 8);
      xb0 = *(const h16x8*)pB; xb1 = *(const h16x8*)(pB + 8);
    }

    // z += W_hh h_prev — each weight fragment feeds TWO MFMAs (A and B)
    #pragma unroll
    for (int s = 0; s < 16; ++s) {
      h16x8 bhA = *(const h16x8*)&hA[lr * HPAD + 32 * s + 8 * lk];
      h16x8 bhB = *(const h16x8*)&hB[lr * HPAD + 32 * s + 8 * lk];
      #pragma unroll
      for (int m = 0; m < 4; ++m) {
        const int id = s * 4 + m;
        h16x8 a = (id < NREG)
            ? areg[id]
            : *(const h16x8*)&aslice[(size_t)((id - NREG) * 8 + wave) * 512 + lane * 8];
        accA[m] = __builtin_amdgcn_mfma_f32_16x16x32_f16(a, bhA, accA[m], 0, 0, 0);
        accB[m] = __builtin_amdgcn_mfma_f32_16x16x32_f16(a, bhB, accB[m], 0, 0, 0);
      }
    }

    __syncthreads();   // all LDS reads of h(t-1) complete before overwrite

    // h_t = tanh(z): write LDS (single-buffered) + hall history
    h16* rowA = hall + ((size_t)t * 256 + b0      + lr) * HDIM + wc0 + lk * 4;
    h16* rowB = hall + ((size_t)t * 256 + b0 + 16 + lr) * HDIM + wc0 + lk * 4;
    #pragma unroll
    for (int m = 0; m < 4; ++m) {
      h16x4 hvA, hvB;
      #pragma unroll
      for (int i = 0; i < 4; ++i) {
        hvA[i] = (h16)fast_tanh(accA[m][i]);
        hvB[i] = (h16)fast_tanh(accB[m][i]);
      }
      *(h16x4*)&hA[lr * HPAD + wc0 + 16 * m + 4 * lk] = hvA;
      *(h16x4*)&hB[lr * HPAD + wc0 + 16 * m + 4 * lk] = hvB;
      *(h16x4*)(rowA + 16 * m) = hvA;
      *(h16x4*)(rowB + 16 * m) = hvB;
    }

    __syncthreads();   // h(t) visible to all before next step's reads
  }
}

// ---------------- Epilogue: out = tanh(h_all @ W_ho^T + b_ho) ----------------
__global__ __launch_bounds__(512)
void out_all(const h16* __restrict__ hall, const float* __restrict__ Who,
             const float* __restrict__ bho, float* __restrict__ out)
{
  __shared__ h16 wholds[NOUT * HPAD];   // 24960 B

  const int tid  = threadIdx.x;
  const int wave = tid >> 6;
  const int lane = tid & 63;
  const int lr   = lane & 15;
  const int lk   = lane >> 4;

  for (int idx = tid; idx < NOUT * HDIM; idx += 512) {
    int r = idx >> 9, k = idx & 511;
    wholds[r * HPAD + k] = (h16)Who[idx];
  }

  f32x4 o0, o1;
  { o0 = *(const f32x4*)&bho[lk * 4]; }
  { int ob = 16 + lk * 4;
    if (ob < NOUT) o1 = *(const f32x4*)&bho[ob];
    else { o1[0] = 0.f; o1[1] = 0.f; o1[2] = 0.f; o1[3] = 0.f; } }
  __syncthreads();

  const int rt = blockIdx.x * 8 + wave;
  const int t  = rt >> 4;
  const int b  = (rt & 15) * 16 + lr;
  const int row1 = (16 + lr < NOUT) ? (16 + lr) : (8 + lr);

  const h16* hrow = hall + ((size_t)t * 256 + b) * HDIM + lk * 8;

  #pragma unroll
  for (int s = 0; s < 16; ++s) {
    h16x8 bh = *(const h16x8*)(hrow + 32 * s);
    h16x8 a0 = *(const h16x8*)&wholds[lr * HPAD + s * 32 + lk * 8];
    h16x8 a1 = *(const h16x8*)&wholds[row1 * HPAD + s * 32 + lk * 8];
    o0 = __builtin_amdgcn_mfma_f32_16x16x32_f16(a0, bh, o0, 0, 0, 0);
    o1 = __builtin_amdgcn_mfma_f32_16x16x32_f16(a1, bh, o1, 0, 0, 0);
  }

  float* op = out + ((size_t)b * TSTEPS + t) * NOUT;
  f32x4 v0;
  #pragma unroll
  for (int i = 0; i < 4; ++i) v0[i] = fast_tanh(o0[i]);
  *(f32x4*)(op + lk * 4) = v0;
  if (lk < 2) {
    f32x4 v1;
    #pragma unroll
    for (int i = 0; i < 4; ++i) v1[i] = fast_tanh(o1[i]);
    *(f32x4*)(op + 16 + lk * 4) = v1;
  }
}

// ---------------- Path C: fully self-contained fallback ----------------------
__device__ __forceinline__ void out_proj(
    int t, const h16* __restrict__ hb, const h16* __restrict__ who,
    f32x4 bho0, f32x4 bho1, float* __restrict__ out, int b0, int lr, int lk)
{
  f32x4 o0 = bho0, o1 = bho1;
  const int row1 = (16 + lr < NOUT) ? (16 + lr) : (8 + lr);
  #pragma unroll
  for (int s = 0; s < 16; ++s) {
    h16x8 bh = *(const h16x8*)&hb[lr * HPAD + s * 32 + lk * 8];
    h16x8 a0 = *(const h16x8*)&who[lr * HPAD + s * 32 + lk * 8];
    h16x8 a1 = *(const h16x8*)&who[row1 * HPAD + s * 32 + lk * 8];
    o0 = __builtin_amdgcn_mfma_f32_16x16x32_f16(a0, bh, o0, 0, 0, 0);
    o1 = __builtin_amdgcn_mfma_f32_16x16x32_f16(a1, bh, o1, 0, 0, 0);
  }
  float* op = out + ((size_t)(b0 + lr) * TSTEPS + t) * NOUT;
  f32x4 v0;
  #pragma unroll
  for (int i = 0; i < 4; ++i) v0[i] = fast_tanh(o0[i]);
  *(f32x4*)(op + lk * 4) = v0;
  if (lk < 2) {
    f32x4 v1;
    #pragma unroll
    for (int i = 0; i < 4; ++i) v1[i] = fast_tanh(o1[i]);
    *(f32x4*)(op + 16 + lk * 4) = v1;
  }
}

__global__ __launch_bounds__(512, 2)
void rnn_fused(const float* __restrict__ x,
               const float* __restrict__ Wih,
               const float* __restrict__ Whh,
               const float* __restrict__ bih,
               const float* __restrict__ bhh,
               const float* __restrict__ Who,
               const float* __restrict__ bho,
               float* __restrict__ out)
{
  __shared__ h16 hbuf[2][BB * HPAD];
  __shared__ h16 xbuf[2][BB * XPAD];
  __shared__ h16 wholds[NOUT * HPAD];

  const int tid  = threadIdx.x;
  const int wave = tid >> 6;
  const int lane = tid & 63;
  const int lr   = lane & 15;
  const int lk   = lane >> 4;
  const int b0   = blockIdx.x * BB;
  const int wc0  = wave * 64;

  h16x8 a_rec[4][16];
  #pragma unroll
  for (int m = 0; m < 4; ++m) {
    const int row = wc0 + m * 16 + lr;
    #pragma unroll
    for (int s = 0; s < 16; ++s)
      a_rec[m][s] = cvt8(Whh + (size_t)row * HDIM + s * 32 + lk * 8);
  }
  h16x8 a_ih[4][2];
  #pragma unroll
  for (int m = 0; m < 4; ++m) {
    const int row = wc0 + m * 16 + lr;
    #pragma unroll
    for (int s = 0; s < 2; ++s)
      a_ih[m][s] = cvt8(Wih + (size_t)row * NIN + s * 32 + lk * 8);
  }
  f32x4 biasv[4];
  #pragma unroll
  for (int m = 0; m < 4; ++m) {
    const int c = wc0 + m * 16 + lk * 4;
    f32x4 bi = *(const f32x4*)&bih[c];
    f32x4 bh2 = *(const f32x4*)&bhh[c];
    biasv[m] = bi + bh2;
  }
  f32x4 bho0, bho1;
  { bho0 = *(const f32x4*)&bho[lk * 4]; }
  { int ob = 16 + lk * 4;
    if (ob < NOUT) bho1 = *(const f32x4*)&bho[ob];
    else { bho1[0] = 0.f; bho1[1] = 0.f; bho1[2] = 0.f; bho1[3] = 0.f; } }

  for (int idx = tid; idx < NOUT * HDIM; idx += 512) {
    int r = idx >> 9, k = idx & 511;
    wholds[r * HPAD + k] = (h16)Who[idx];
  }
  for (int idx = tid; idx < BB * HPAD; idx += 512) hbuf[0][idx] = (h16)0.f;
  {
    int r = tid >> 5, c2 = (tid & 31) * 2;
    f32x2 v = *(const f32x2*)(x + ((size_t)(b0 + r) * TSTEPS + 0) * NIN + c2);
    h16x2 pk = { (h16)v.x, (h16)v.y };
    *(h16x2*)&xbuf[0][r * XPAD + c2] = pk;
  }
  __syncthreads();

  for (int t = 0; t < TSTEPS; ++t) {
    const h16* hb = hbuf[t & 1];
    h16*       hn = hbuf[(t + 1) & 1];
    const h16* xb = xbuf[t & 1];
    h16*       xn = xbuf[(t + 1) & 1];

    if (t > 0 && wave == ((t - 1) & 7))
      out_proj(t - 1, hb, wholds, bho0, bho1, out, b0, lr, lk);

    const int tl = (t + 1 < TSTEPS) ? (t + 1) : (TSTEPS - 1);
    const int xr = tid >> 5, xc = (tid & 31) * 2;
    f32x2 xv = *(const f32x2*)(x + ((size_t)(b0 + xr) * TSTEPS + tl) * NIN + xc);

    f32x4 acc[4];
    #pragma unroll
    for (int m = 0; m < 4; ++m) acc[m] = biasv[m];
    #pragma unroll
    for (int s = 0; s < 2; ++s) {
      h16x8 bx = *(const h16x8*)&xb[lr * XPAD + s * 32 + lk * 8];
      #pragma unroll
      for (int m = 0; m < 4; ++m)
        acc[m] = __builtin_amdgcn_mfma_f32_16x16x32_f16(a_ih[m][s], bx, acc[m], 0, 0, 0);
    }
    #pragma unroll
    for (int s = 0; s < 16; ++s) {
      h16x8 bh = *(const h16x8*)&hb[lr * HPAD + 32 * s + 8 * lk];
      #pragma unroll
      for (int m = 0; m < 4; ++m)
        acc[m] = __builtin_amdgcn_mfma_f32_16x16x32_f16(a_rec[m][s], bh, acc[m], 0, 0, 0);
    }
    #pragma unroll
    for (int m = 0; m < 4; ++m) {
      h16x4 hv;
      #pragma unroll
      for (int i = 0; i < 4; ++i) hv[i] = (h16)fast_tanh(acc[m][i]);
      *(h16x4*)&hn[lr * HPAD + wc0 + 16 * m + 4 * lk] = hv;
    }
    {
      h16x2 pk = { (h16)xv.x, (h16)xv.y };
      *(h16x2*)&xn[xr * XPAD + xc] = pk;
    }
    __syncthreads();
  }

  if (wave == ((TSTEPS - 1) & 7))
    out_proj(TSTEPS - 1, hbuf[TSTEPS & 1], wholds, bho0, bho1, out, b0, lr, lk);
}

extern "C" void kernel_launch(void* const* d_in, const int* in_sizes, int n_in,
                              void* d_out, int out_size, void* d_ws, size_t ws_size,
                              hipStream_t stream) {
  (void)in_sizes; (void)n_in; (void)out_size;
  const float* x   = (const float*)d_in[0];
  const float* Wih = (const float*)d_in[1];
  const float* Whh = (const float*)d_in[2];
  const float* bih = (const float*)d_in[3];
  const float* bhh = (const float*)d_in[4];
  const float* Who = (const float*)d_in[5];
  const float* bho = (const float*)d_in[6];
  float* out = (float*)d_out;

  const size_t XP_BYTES   = (size_t)TSTEPS * 256 * HDIM * sizeof(h16);  // 128 MiB
  const size_t HALL_BYTES = (size_t)TSTEPS * 256 * HDIM * sizeof(h16);  // 128 MiB

  if (ws_size >= XP_BYTES + HALL_BYTES) {
    h16* xp   = (h16*)d_ws;
    h16* hall = (h16*)((char*)d_ws + XP_BYTES);
    xp_gemm<<<dim3(256), dim3(512), 0, stream>>>(x, Wih, bih, bhh, xp);
    rnn_core3<<<dim3(8), dim3(512), 0, stream>>>(Whh, xp, hall);
    out_all<<<dim3(1024), dim3(512), 0, stream>>>(hall, Who, bho, out);
  } else {
    rnn_fused<<<dim3(256 / BB), dim3(512), 0, stream>>>(x, Wih, Whh, bih, bhh, Who, bho, out);
  }
}

// Round 7
// 1280.412 us; speedup vs baseline: 2.9356x; 2.1190x over previous
//
#include <hip/hip_runtime.h>
#include <cstdint>
#include <cstddef>

// RNN: B=256, T=512, H=512, I=64, O=24. fp32 in/out.
//
// v7 structure:
//  Path A4 (ws >= 256 MiB):
//    1) xp_gemm: xp[b][t][:] = W_ih x + b_ih + b_hh (f16, permuted) -> ws[0,128Mi)
//    2) rnn_core4: 32 blocks x 512 thr, BB=8 batch rows per block (batch
//       spread over 2x the CUs). Lanes lr and lr+8 read the SAME h LDS
//       address (2-way broadcast, free) -> h-read data per wave halves while
//       the per-CU weight stream (49 reg slots + 15 LDS slots) is unchanged.
//       hall history stores DEFERRED one step (pend regs) so the barrier's
//       vmcnt(0) drain doesn't eat the store-ack latency each step.
//    3) out_all: full-chip epilogue out = tanh(h_all @ W_ho^T + b_ho).
//  Fallback: self-contained round-0 kernel (~4.4 ms).
//
//  Hard constraints learned (r0/r5/r6, measured):
//   - reg budget 256/lane at 8 waves/CU; W_hh alone = whole CU reg file ->
//     >250 regs/lane spills to scratch = 2.5-3.5x regression. NREG=49 is max safe.
//   - per-step cross-CU sync (agent-scope acq/rel) = L2 flush ~6us/step -> never.

#define TSTEPS 512
#define HDIM   512
#define NIN    64
#define NOUT   24
#define BB     16
#define HPAD   520
#define XPAD   72
#define NREG   49
#define NLDS   (64 - NREG)   // 15

typedef _Float16 h16;
typedef __attribute__((ext_vector_type(8))) _Float16 h16x8;
typedef __attribute__((ext_vector_type(4))) _Float16 h16x4;
typedef __attribute__((ext_vector_type(2))) _Float16 h16x2;
typedef __attribute__((ext_vector_type(4))) float    f32x4;
typedef __attribute__((ext_vector_type(2))) float    f32x2;

__device__ __forceinline__ float fast_tanh(float z) {
  float e = __builtin_amdgcn_exp2f(z * 2.8853900817779268f);
  return 1.0f - 2.0f * __builtin_amdgcn_rcpf(e + 1.0f);
}

__device__ __forceinline__ h16x8 cvt8(const float* __restrict__ p) {
  f32x4 f0 = *(const f32x4*)p;
  f32x4 f1 = *(const f32x4*)(p + 4);
  h16x8 a;
  #pragma unroll
  for (int j = 0; j < 4; ++j) { a[j] = (h16)f0[j]; a[4 + j] = (h16)f1[j]; }
  return a;
}

// ---------------- Prologue: xp = W_ih x + b_ih + b_hh, permuted f16 ----------
// chunk ((t*16+g)*8+wave)*64+lane holds 16 h16:
// [m*4+i] = xp[batch=16g+(lane&15)][t][col=64*wave+16m+4*(lane>>4)+i]
__global__ __launch_bounds__(512)
void xp_gemm(const float* __restrict__ x, const float* __restrict__ Wih,
             const float* __restrict__ bih, const float* __restrict__ bhh,
             h16* __restrict__ xp)
{
  const int tid  = threadIdx.x;
  const int wave = tid >> 6;
  const int lane = tid & 63;
  const int lr   = lane & 15;
  const int lk   = lane >> 4;
  const int blk  = blockIdx.x & 15;
  const int tc   = blockIdx.x >> 4;
  const int c0   = wave * 64;

  h16x8 A[4][2];
  #pragma unroll
  for (int m = 0; m < 4; ++m)
    #pragma unroll
    for (int s = 0; s < 2; ++s)
      A[m][s] = cvt8(Wih + (size_t)(c0 + 16 * m + lr) * NIN + 32 * s + 8 * lk);

  f32x4 bias[4];
  #pragma unroll
  for (int m = 0; m < 4; ++m) {
    const int c = c0 + 16 * m + 4 * lk;
    f32x4 bi = *(const f32x4*)&bih[c];
    f32x4 bh = *(const f32x4*)&bhh[c];
    bias[m] = bi + bh;
  }

  const float* xrow = x + (size_t)(16 * blk + lr) * (TSTEPS * NIN);

  for (int j = 0; j < 32; ++j) {
    const int t = tc * 32 + j;
    f32x4 acc[4];
    #pragma unroll
    for (int m = 0; m < 4; ++m) acc[m] = bias[m];
    #pragma unroll
    for (int s = 0; s < 2; ++s) {
      h16x8 bx = cvt8(xrow + (size_t)t * NIN + 32 * s + 8 * lk);
      #pragma unroll
      for (int m = 0; m < 4; ++m)
        acc[m] = __builtin_amdgcn_mfma_f32_16x16x32_f16(A[m][s], bx, acc[m], 0, 0, 0);
    }
    h16x8 c0v, c1v;
    #pragma unroll
    for (int i = 0; i < 4; ++i) {
      c0v[i]     = (h16)acc[0][i];
      c0v[4 + i] = (h16)acc[1][i];
      c1v[i]     = (h16)acc[2][i];
      c1v[4 + i] = (h16)acc[3][i];
    }
    h16* p = xp + ((((size_t)t * 16 + blk) * 8 + wave) * 64 + lane) * 16;
    *(h16x8*)p       = c0v;
    *(h16x8*)(p + 8) = c1v;
  }
}

// ---------------- Path A4: BB=8 recurrence, 32 blocks -------------------------
__global__ __launch_bounds__(512, 2)
void rnn_core4(const float* __restrict__ Whh, const h16* __restrict__ xp,
               h16* __restrict__ hall)
{
  __shared__ h16 hbuf[2][8 * HPAD];         // 16640 B  (8 batch rows)
  __shared__ h16 aslice[NLDS * 8 * 512];    // 122880 B -> total 139520 B

  const int tid  = threadIdx.x;
  const int wave = tid >> 6;
  const int lane = tid & 63;
  const int lr   = lane & 15;
  const int lr7  = lane & 7;
  const int lk   = lane >> 4;
  const int blk  = blockIdx.x;        // 0..31
  const int g    = blk >> 1;          // xp 16-row group
  const int hf   = blk & 1;           // which 8-row half of the group
  const int b0   = blk * 8;           // first batch row of this block
  const int wc0  = wave * 64;

  // W_hh fragments: slot id = s*4+m; id < NREG -> regs, else LDS.
  h16x8 areg[NREG];
  #pragma unroll
  for (int s = 0; s < 16; ++s) {
    #pragma unroll
    for (int m = 0; m < 4; ++m) {
      h16x8 a = cvt8(Whh + (size_t)(wc0 + 16 * m + lr) * HDIM + 32 * s + 8 * lk);
      const int id = s * 4 + m;
      if (id < NREG) areg[id] = a;
      else *(h16x8*)&aslice[(size_t)((id - NREG) * 8 + wave) * 512 + lane * 8] = a;
    }
  }

  for (int idx = tid; idx < 8 * HPAD; idx += 512) hbuf[0][idx] = (h16)0.f;
  __syncthreads();

  // xp lane remap: batch row = 16g + 8hf + lr7, k-group = lk
  const int lane_sel = lk * 16 + hf * 8 + lr7;

  // preload xp(0)
  h16x8 xr0, xr1;
  {
    const h16* p = xp + (((size_t)g * 8 + wave) * 64 + lane_sel) * 16;
    xr0 = *(const h16x8*)p;
    xr1 = *(const h16x8*)(p + 8);
  }

  h16x4 pend[4];
  h16*  pendRow = hall;   // dummy init; first use gated by t>0 && lr<8

  for (int t = 0; t < TSTEPS; ++t) {
    const h16* hb = hbuf[t & 1];
    h16*       hn = hbuf[(t + 1) & 1];

    // deferred hall stores for step t-1 (complete during this step's compute)
    if (t > 0 && lr < 8) {
      #pragma unroll
      for (int m = 0; m < 4; ++m)
        *(h16x4*)(pendRow + 16 * m) = pend[m];
    }

    // acc init from prefetched xp(t)
    f32x4 acc[4];
    #pragma unroll
    for (int i = 0; i < 4; ++i) {
      acc[0][i] = (float)xr0[i];
      acc[1][i] = (float)xr0[4 + i];
      acc[2][i] = (float)xr1[i];
      acc[3][i] = (float)xr1[4 + i];
    }

    // prefetch xp(t+1)
    {
      const int tn = (t + 1 < TSTEPS) ? (t + 1) : t;
      const h16* p = xp + ((((size_t)tn * 16 + g) * 8 + wave) * 64 + lane_sel) * 16;
      xr0 = *(const h16x8*)p;
      xr1 = *(const h16x8*)(p + 8);
    }

    // z += W_hh h_prev ; lanes lr and lr+8 read the same address (broadcast)
    #pragma unroll
    for (int s = 0; s < 16; ++s) {
      h16x8 bh = *(const h16x8*)&hb[lr7 * HPAD + 32 * s + 8 * lk];
      #pragma unroll
      for (int m = 0; m < 4; ++m) {
        const int id = s * 4 + m;
        h16x8 a = (id < NREG)
            ? areg[id]
            : *(const h16x8*)&aslice[(size_t)((id - NREG) * 8 + wave) * 512 + lane * 8];
        acc[m] = __builtin_amdgcn_mfma_f32_16x16x32_f16(a, bh, acc[m], 0, 0, 0);
      }
    }

    // h_t = tanh(z); lane -> batch col lr (lr>=8 duplicates, masked on write)
    #pragma unroll
    for (int m = 0; m < 4; ++m) {
      h16x4 hv;
      #pragma unroll
      for (int i = 0; i < 4; ++i) hv[i] = (h16)fast_tanh(acc[m][i]);
      if (lr < 8)
        *(h16x4*)&hn[lr7 * HPAD + wc0 + 16 * m + 4 * lk] = hv;
      pend[m] = hv;
    }
    pendRow = hall + ((size_t)t * 256 + b0 + lr7) * HDIM + wc0 + lk * 4;

    __syncthreads();   // hn complete (and pend stores of t-1 drained)
  }

  // flush final pending hall stores (t = 511)
  if (lr < 8) {
    #pragma unroll
    for (int m = 0; m < 4; ++m)
      *(h16x4*)(pendRow + 16 * m) = pend[m];
  }
}

// ---------------- Epilogue: out = tanh(h_all @ W_ho^T + b_ho) ----------------
__global__ __launch_bounds__(512)
void out_all(const h16* __restrict__ hall, const float* __restrict__ Who,
             const float* __restrict__ bho, float* __restrict__ out)
{
  __shared__ h16 wholds[NOUT * HPAD];   // 24960 B

  const int tid  = threadIdx.x;
  const int wave = tid >> 6;
  const int lane = tid & 63;
  const int lr   = lane & 15;
  const int lk   = lane >> 4;

  for (int idx = tid; idx < NOUT * HDIM; idx += 512) {
    int r = idx >> 9, k = idx & 511;
    wholds[r * HPAD + k] = (h16)Who[idx];
  }

  f32x4 o0, o1;
  { o0 = *(const f32x4*)&bho[lk * 4]; }
  { int ob = 16 + lk * 4;
    if (ob < NOUT) o1 = *(const f32x4*)&bho[ob];
    else { o1[0] = 0.f; o1[1] = 0.f; o1[2] = 0.f; o1[3] = 0.f; } }
  __syncthreads();

  const int rt = blockIdx.x * 8 + wave;
  const int t  = rt >> 4;
  const int b  = (rt & 15) * 16 + lr;
  const int row1 = (16 + lr < NOUT) ? (16 + lr) : (8 + lr);

  const h16* hrow = hall + ((size_t)t * 256 + b) * HDIM + lk * 8;

  #pragma unroll
  for (int s = 0; s < 16; ++s) {
    h16x8 bh = *(const h16x8*)(hrow + 32 * s);
    h16x8 a0 = *(const h16x8*)&wholds[lr * HPAD + s * 32 + lk * 8];
    h16x8 a1 = *(const h16x8*)&wholds[row1 * HPAD + s * 32 + lk * 8];
    o0 = __builtin_amdgcn_mfma_f32_16x16x32_f16(a0, bh, o0, 0, 0, 0);
    o1 = __builtin_amdgcn_mfma_f32_16x16x32_f16(a1, bh, o1, 0, 0, 0);
  }

  float* op = out + ((size_t)b * TSTEPS + t) * NOUT;
  f32x4 v0;
  #pragma unroll
  for (int i = 0; i < 4; ++i) v0[i] = fast_tanh(o0[i]);
  *(f32x4*)(op + lk * 4) = v0;
  if (lk < 2) {
    f32x4 v1;
    #pragma unroll
    for (int i = 0; i < 4; ++i) v1[i] = fast_tanh(o1[i]);
    *(f32x4*)(op + 16 + lk * 4) = v1;
  }
}

// ---------------- Path C: fully self-contained fallback ----------------------
__device__ __forceinline__ void out_proj(
    int t, const h16* __restrict__ hb, const h16* __restrict__ who,
    f32x4 bho0, f32x4 bho1, float* __restrict__ out, int b0, int lr, int lk)
{
  f32x4 o0 = bho0, o1 = bho1;
  const int row1 = (16 + lr < NOUT) ? (16 + lr) : (8 + lr);
  #pragma unroll
  for (int s = 0; s < 16; ++s) {
    h16x8 bh = *(const h16x8*)&hb[lr * HPAD + s * 32 + lk * 8];
    h16x8 a0 = *(const h16x8*)&who[lr * HPAD + s * 32 + lk * 8];
    h16x8 a1 = *(const h16x8*)&who[row1 * HPAD + s * 32 + lk * 8];
    o0 = __builtin_amdgcn_mfma_f32_16x16x32_f16(a0, bh, o0, 0, 0, 0);
    o1 = __builtin_amdgcn_mfma_f32_16x16x32_f16(a1, bh, o1, 0, 0, 0);
  }
  float* op = out + ((size_t)(b0 + lr) * TSTEPS + t) * NOUT;
  f32x4 v0;
  #pragma unroll
  for (int i = 0; i < 4; ++i) v0[i] = fast_tanh(o0[i]);
  *(f32x4*)(op + lk * 4) = v0;
  if (lk < 2) {
    f32x4 v1;
    #pragma unroll
    for (int i = 0; i < 4; ++i) v1[i] = fast_tanh(o1[i]);
    *(f32x4*)(op + 16 + lk * 4) = v1;
  }
}

__global__ __launch_bounds__(512, 2)
void rnn_fused(const float* __restrict__ x,
               const float* __restrict__ Wih,
               const float* __restrict__ Whh,
               const float* __restrict__ bih,
               const float* __restrict__ bhh,
               const float* __restrict__ Who,
               const float* __restrict__ bho,
               float* __restrict__ out)
{
  __shared__ h16 hbuf[2][BB * HPAD];
  __shared__ h16 xbuf[2][BB * XPAD];
  __shared__ h16 wholds[NOUT * HPAD];

  const int tid  = threadIdx.x;
  const int wave = tid >> 6;
  const int lane = tid & 63;
  const int lr   = lane & 15;
  const int lk   = lane >> 4;
  const int b0   = blockIdx.x * BB;
  const int wc0  = wave * 64;

  h16x8 a_rec[4][16];
  #pragma unroll
  for (int m = 0; m < 4; ++m) {
    const int row = wc0 + m * 16 + lr;
    #pragma unroll
    for (int s = 0; s < 16; ++s)
      a_rec[m][s] = cvt8(Whh + (size_t)row * HDIM + s * 32 + lk * 8);
  }
  h16x8 a_ih[4][2];
  #pragma unroll
  for (int m = 0; m < 4; ++m) {
    const int row = wc0 + m * 16 + lr;
    #pragma unroll
    for (int s = 0; s < 2; ++s)
      a_ih[m][s] = cvt8(Wih + (size_t)row * NIN + s * 32 + lk * 8);
  }
  f32x4 biasv[4];
  #pragma unroll
  for (int m = 0; m < 4; ++m) {
    const int c = wc0 + m * 16 + lk * 4;
    f32x4 bi = *(const f32x4*)&bih[c];
    f32x4 bh2 = *(const f32x4*)&bhh[c];
    biasv[m] = bi + bh2;
  }
  f32x4 bho0, bho1;
  { bho0 = *(const f32x4*)&bho[lk * 4]; }
  { int ob = 16 + lk * 4;
    if (ob < NOUT) bho1 = *(const f32x4*)&bho[ob];
    else { bho1[0] = 0.f; bho1[1] = 0.f; bho1[2] = 0.f; bho1[3] = 0.f; } }

  for (int idx = tid; idx < NOUT * HDIM; idx += 512) {
    int r = idx >> 9, k = idx & 511;
    wholds[r * HPAD + k] = (h16)Who[idx];
  }
  for (int idx = tid; idx < BB * HPAD; idx += 512) hbuf[0][idx] = (h16)0.f;
  {
    int r = tid >> 5, c2 = (tid & 31) * 2;
    f32x2 v = *(const f32x2*)(x + ((size_t)(b0 + r) * TSTEPS + 0) * NIN + c2);
    h16x2 pk = { (h16)v.x, (h16)v.y };
    *(h16x2*)&xbuf[0][r * XPAD + c2] = pk;
  }
  __syncthreads();

  for (int t = 0; t < TSTEPS; ++t) {
    const h16* hb = hbuf[t & 1];
    h16*       hn = hbuf[(t + 1) & 1];
    const h16* xb = xbuf[t & 1];
    h16*       xn = xbuf[(t + 1) & 1];

    if (t > 0 && wave == ((t - 1) & 7))
      out_proj(t - 1, hb, wholds, bho0, bho1, out, b0, lr, lk);

    const int tl = (t + 1 < TSTEPS) ? (t + 1) : (TSTEPS - 1);
    const int xr = tid >> 5, xc = (tid & 31) * 2;
    f32x2 xv = *(const f32x2*)(x + ((size_t)(b0 + xr) * TSTEPS + tl) * NIN + xc);

    f32x4 acc[4];
    #pragma unroll
    for (int m = 0; m < 4; ++m) acc[m] = biasv[m];
    #pragma unroll
    for (int s = 0; s < 2; ++s) {
      h16x8 bx = *(const h16x8*)&xb[lr * XPAD + s * 32 + lk * 8];
      #pragma unroll
      for (int m = 0; m < 4; ++m)
        acc[m] = __builtin_amdgcn_mfma_f32_16x16x32_f16(a_ih[m][s], bx, acc[m], 0, 0, 0);
    }
    #pragma unroll
    for (int s = 0; s < 16; ++s) {
      h16x8 bh = *(const h16x8*)&hb[lr * HPAD + 32 * s + 8 * lk];
      #pragma unroll
      for (int m = 0; m < 4; ++m)
        acc[m] = __builtin_amdgcn_mfma_f32_16x16x32_f16(a_rec[m][s], bh, acc[m], 0, 0, 0);
    }
    #pragma unroll
    for (int m = 0; m < 4; ++m) {
      h16x4 hv;
      #pragma unroll
      for (int i = 0; i < 4; ++i) hv[i] = (h16)fast_tanh(acc[m][i]);
      *(h16x4*)&hn[lr * HPAD + wc0 + 16 * m + 4 * lk] = hv;
    }
    {
      h16x2 pk = { (h16)xv.x, (h16)xv.y };
      *(h16x2*)&xn[xr * XPAD + xc] = pk;
    }
    __syncthreads();
  }

  if (wave == ((TSTEPS - 1) & 7))
    out_proj(TSTEPS - 1, hbuf[TSTEPS & 1], wholds, bho0, bho1, out, b0, lr, lk);
}

extern "C" void kernel_launch(void* const* d_in, const int* in_sizes, int n_in,
                              void* d_out, int out_size, void* d_ws, size_t ws_size,
                              hipStream_t stream) {
  (void)in_sizes; (void)n_in; (void)out_size;
  const float* x   = (const float*)d_in[0];
  const float* Wih = (const float*)d_in[1];
  const float* Whh = (const float*)d_in[2];
  const float* bih = (const float*)d_in[3];
  const float* bhh = (const float*)d_in[4];
  const float* Who = (const float*)d_in[5];
  const float* bho = (const float*)d_in[6];
  float* out = (float*)d_out;

  const size_t XP_BYTES   = (size_t)TSTEPS * 256 * HDIM * sizeof(h16);  // 128 MiB
  const size_t HALL_BYTES = (size_t)TSTEPS * 256 * HDIM * sizeof(h16);  // 128 MiB

  if (ws_size >= XP_BYTES + HALL_BYTES) {
    h16* xp   = (h16*)d_ws;
    h16* hall = (h16*)((char*)d_ws + XP_BYTES);
    xp_gemm<<<dim3(256), dim3(512), 0, stream>>>(x, Wih, bih, bhh, xp);
    rnn_core4<<<dim3(32), dim3(512), 0, stream>>>(Whh, xp, hall);
    out_all<<<dim3(1024), dim3(512), 0, stream>>>(hall, Who, bho, out);
  } else {
    rnn_fused<<<dim3(256 / BB), dim3(512), 0, stream>>>(x, Wih, Whh, bih, bhh, Who, bho, out);
  }
}